// Round 1
// baseline (781.107 us; speedup 1.0000x reference)
//
#include <hip/hip_runtime.h>

#define WPB 8   // windows per block

typedef short bf16x8 __attribute__((ext_vector_type(8)));
typedef float f32x4 __attribute__((ext_vector_type(4)));

__device__ __forceinline__ unsigned cvt_pk_bf16(float lo, float hi) {
  unsigned r;
  asm("v_cvt_pk_bf16_f32 %0, %1, %2" : "=v"(r) : "v"(lo), "v"(hi));
  return r;
}

__device__ __forceinline__ bf16x8 pack4(unsigned a, unsigned b, unsigned c, unsigned d) {
  union { unsigned u[4]; bf16x8 v; } t;
  t.u[0] = a; t.u[1] = b; t.u[2] = c; t.u[3] = d;
  return t.v;
}

__device__ __forceinline__ unsigned short f2bf(float f) {
  unsigned u = __float_as_uint(f);
  unsigned r = (u + 0x7fffu + ((u >> 16) & 1u)) >> 16;
  return (unsigned short)r;
}

// Workgroup barrier that drains ONLY lgkmcnt (LDS). Unlike __syncthreads(),
// global loads/stores stay in flight across it (no vmcnt(0) drain), so the
// cross-window x prefetch and the NT out-stores overlap the next phases.
// Single volatile asm with memory clobber: C-level LDS ops cannot cross it.
__device__ __forceinline__ void bar_lds() {
  asm volatile("s_waitcnt lgkmcnt(0)\n\ts_barrier" ::: "memory");
}

// ---------------------------------------------------------------------------
// Prep kernel (unchanged):
//  blocks 0..31 : W_qkv (6144 frags) and proj_w (2048 frags, k-permuted)
//  block 32     : CPB MLP -> rpb packed as MFMA C-fragments for swapped S^T
// ---------------------------------------------------------------------------
__global__ __launch_bounds__(256) void prep(
    const float* __restrict__ W_qkv, const float* __restrict__ proj_w,
    const float* __restrict__ cpb_w1, const float* __restrict__ cpb_b1,
    const float* __restrict__ cpb_w2, const float* __restrict__ rel_table,
    const int* __restrict__ rel_index,
    bf16x8* __restrict__ wq, bf16x8* __restrict__ wp, float* __restrict__ rpbf)
{
  const int b = blockIdx.x, t = threadIdx.x;
  if (b < 32) {
    int g = b * 256 + t;               // [0, 8192)
    if (g < 6144) {
      int c = g >> 8, kk = (g >> 6) & 3, l = g & 63;
      const float* s = W_qkv + (c * 16 + (l & 15)) * 128 + kk * 32 + (l >> 4) * 8;
      bf16x8 v;
      #pragma unroll
      for (int j = 0; j < 8; ++j) v[j] = (short)f2bf(s[j]);
      wq[g] = v;
    } else {
      int gl = g - 6144;
      int c = gl >> 8, kk = (gl >> 6) & 3, l = gl & 63;
      const float* row = proj_w + (c * 16 + (l & 15)) * 128;
      bf16x8 v;
      #pragma unroll
      for (int j = 0; j < 8; ++j)
        v[j] = (short)f2bf(row[kk * 32 + (j >> 2) * 16 + (l >> 4) * 4 + (j & 3)]);
      wp[gl] = v;
    }
  } else {
    __shared__ float bt[900];
    if (t < 225) {
      float t0 = rel_table[t * 2], t1 = rel_table[t * 2 + 1];
      float a0 = 0.f, a1 = 0.f, a2 = 0.f, a3 = 0.f;
      for (int j = 0; j < 512; ++j) {
        float hm = fmaxf(t0 * cpb_w1[j * 2] + t1 * cpb_w1[j * 2 + 1] + cpb_b1[j], 0.f);
        a0 += hm * cpb_w2[j];
        a1 += hm * cpb_w2[512 + j];
        a2 += hm * cpb_w2[1024 + j];
        a3 += hm * cpb_w2[1536 + j];
      }
      bt[t * 4 + 0] = a0; bt[t * 4 + 1] = a1;
      bt[t * 4 + 2] = a2; bt[t * 4 + 3] = a3;
    }
    __syncthreads();
    for (int i = t; i < 16384; i += 256) {
      int hrc = i >> 8, lane = (i >> 2) & 63, j = i & 3;
      int hh = hrc >> 4, r = (hrc >> 2) & 3, c = hrc & 3;
      int n = r * 16 + (lane & 15);
      int m = c * 16 + ((lane >> 4) << 2) + j;
      float v = bt[rel_index[n * 64 + m] * 4 + hh];
      rpbf[i] = 16.0f * __fdividef(1.0f, 1.0f + __expf(-v));
    }
  }
}

// ---------------------------------------------------------------------------
// Fused window attention — pipelined multi-window edition.
// Each block processes WPB=8 consecutive windows. LDS = 2 x 16 KB
// double-buffer (Xb overlaid by Ob, as before): the stage-write for window
// w+1 goes to the other buffer, so no barrier is needed between the epilogue
// of w and the staging of w+1.
// Cross-window x prefetch: 8 x float4 into registers, issued AFTER phase-5's
// wp loads (sched_barrier-pinned). vmcnt completes in-order, so any earlier
// issue point would be force-drained by the first younger weight-load wait;
// this placement leaves only the 8 NT stores younger than pf, hiding the
// E-tail + loop-back latency and removing the per-window cold start.
// All barriers are lgkm-only (bar_lds): stores/loads stay in flight.
// pf's live range (E -> next S) does not overlap the phase-1 register peak.
// ---------------------------------------------------------------------------
__global__ __launch_bounds__(256, 4) void win_attn(
    const float* __restrict__ x,
    const float* __restrict__ q_bias,
    const float* __restrict__ v_bias,
    const float* __restrict__ logit_scale,
    const float* __restrict__ proj_b,
    const float* __restrict__ rpbf,
    const bf16x8* __restrict__ wq,
    const bf16x8* __restrict__ wp,
    float* __restrict__ out, int nwin)
{
  __shared__ __align__(128) char lds[2][16384];
  const int tid  = threadIdx.x;
  const int lane = tid & 63;
  const int h    = tid >> 6;     // wave = head
  const int l15  = lane & 15;
  const int l4   = lane >> 4;
  const int swl  = (l15 & 7) << 4;
  const f32x4 fzero = {0.f, 0.f, 0.f, 0.f};

  const int w0 = blockIdx.x * WPB;
  const int rem = nwin - w0;
  const int nw = rem < WPB ? rem : WPB;

  // prologue: issue window w0's loads (only the first window eats the
  // cold-start latency; 7/8 are prefetched under the previous epilogue)
  float4 pf[8];
  {
    const float4* xp = (const float4*)(x + (long)w0 * 8192);
    #pragma unroll
    for (int i = 0; i < 8; ++i) pf[i] = xp[i * 256 + tid];
  }

  for (int w = 0; w < nw; ++w) {
    char* buf = lds[w & 1];
    const long base = (long)(w0 + w) * 8192;

    // pin the weight-stream pointers per-iteration so LICM cannot hoist
    // 100+ regs of loop-invariant fragment loads out of the window loop
    const bf16x8* wql = wq;                 asm("" : "+s"(wql));
    const bf16x8* wpl = wp;                 asm("" : "+s"(wpl));
    const f32x4*  rp  = (const f32x4*)rpbf; asm("" : "+s"(rp));

    // ---- Stage: prefetched fp32 -> swizzled bf16 Xb[64][128]
    #pragma unroll
    for (int i = 0; i < 8; ++i) {
      float4 v = pf[i];
      int e   = (i * 256 + tid) * 4;
      int row = e >> 7;
      int cb  = (e & 127) * 2;
      uint2 pk = { cvt_pk_bf16(v.x, v.y), cvt_pk_bf16(v.z, v.w) };
      *(uint2*)(buf + ((row * 256 + cb) ^ ((row & 7) << 4))) = pk;
    }
    bar_lds();   // Xb ready

    bf16x8 aq[4], bk[4], bv[2][2];

    // ---- Phase 1a: q,k GEMM (swapped: lane d = ct*16+4*l4+reg, n = rt*16+l15)
    {
      f32x4 qT[2][4], kT[2][4];
      #pragma unroll
      for (int ct = 0; ct < 2; ++ct)
        #pragma unroll
        for (int rt = 0; rt < 4; ++rt) { qT[ct][rt] = fzero; kT[ct][rt] = fzero; }

      #pragma unroll
      for (int kk = 0; kk < 4; ++kk) {
        bf16x8 a[4];
        #pragma unroll
        for (int rt = 0; rt < 4; ++rt) {
          int row = rt * 16 + l15;
          a[rt] = *(const bf16x8*)(buf + ((row * 256 + kk * 64 + l4 * 16) ^ swl));
        }
        #pragma unroll
        for (int ct = 0; ct < 2; ++ct) {
          bf16x8 wqf = wql[((2 * h + ct) * 4 + kk) * 64 + lane];
          bf16x8 wkf = wql[((8 + 2 * h + ct) * 4 + kk) * 64 + lane];
          #pragma unroll
          for (int rt = 0; rt < 4; ++rt) {
            qT[ct][rt] = __builtin_amdgcn_mfma_f32_16x16x32_bf16(wqf, a[rt], qT[ct][rt], 0, 0, 0);
            kT[ct][rt] = __builtin_amdgcn_mfma_f32_16x16x32_bf16(wkf, a[rt], kT[ct][rt], 0, 0, 0);
          }
        }
      }

      // ---- normalize q,k; pack S-fragments, lane-local (d-permuted)
      float scale = __expf(fminf(logit_scale[h], 4.6051701859880914f)); // log(100)
      float4 qb0 = *(const float4*)&q_bias[h * 32 + l4 * 4];
      float4 qb1 = *(const float4*)&q_bias[h * 32 + 16 + l4 * 4];
      #pragma unroll
      for (int rt = 0; rt < 4; ++rt) {
        float tq0 = qT[0][rt][0] + qb0.x, tq1 = qT[0][rt][1] + qb0.y;
        float tq2 = qT[0][rt][2] + qb0.z, tq3 = qT[0][rt][3] + qb0.w;
        float tq4 = qT[1][rt][0] + qb1.x, tq5 = qT[1][rt][1] + qb1.y;
        float tq6 = qT[1][rt][2] + qb1.z, tq7 = qT[1][rt][3] + qb1.w;
        float sq = tq0*tq0 + tq1*tq1 + tq2*tq2 + tq3*tq3
                 + tq4*tq4 + tq5*tq5 + tq6*tq6 + tq7*tq7;
        float sk = kT[0][rt][0]*kT[0][rt][0] + kT[0][rt][1]*kT[0][rt][1]
                 + kT[0][rt][2]*kT[0][rt][2] + kT[0][rt][3]*kT[0][rt][3]
                 + kT[1][rt][0]*kT[1][rt][0] + kT[1][rt][1]*kT[1][rt][1]
                 + kT[1][rt][2]*kT[1][rt][2] + kT[1][rt][3]*kT[1][rt][3];
        sq += __shfl_xor(sq, 16); sq += __shfl_xor(sq, 32);
        sk += __shfl_xor(sk, 16); sk += __shfl_xor(sk, 32);
        float iq = __fdividef(scale, fmaxf(sqrtf(sq), 1e-12f));
        float ik = __fdividef(1.0f,  fmaxf(sqrtf(sk), 1e-12f));
        aq[rt] = pack4(cvt_pk_bf16(tq0 * iq, tq1 * iq), cvt_pk_bf16(tq2 * iq, tq3 * iq),
                       cvt_pk_bf16(tq4 * iq, tq5 * iq), cvt_pk_bf16(tq6 * iq, tq7 * iq));
        bk[rt] = pack4(cvt_pk_bf16(kT[0][rt][0] * ik, kT[0][rt][1] * ik),
                       cvt_pk_bf16(kT[0][rt][2] * ik, kT[0][rt][3] * ik),
                       cvt_pk_bf16(kT[1][rt][0] * ik, kT[1][rt][1] * ik),
                       cvt_pk_bf16(kT[1][rt][2] * ik, kT[1][rt][3] * ik));
      }
    }

    // ---- Phase 1b: v GEMM (normal: lane m = rt*16+4*l4+reg, d = ct*16+l15)
    {
      f32x4 vN[2][4];
      #pragma unroll
      for (int ct = 0; ct < 2; ++ct)
        #pragma unroll
        for (int rt = 0; rt < 4; ++rt) vN[ct][rt] = fzero;

      #pragma unroll
      for (int kk = 0; kk < 4; ++kk) {
        bf16x8 a[4];
        #pragma unroll
        for (int rt = 0; rt < 4; ++rt) {
          int row = rt * 16 + l15;
          a[rt] = *(const bf16x8*)(buf + ((row * 256 + kk * 64 + l4 * 16) ^ swl));
        }
        #pragma unroll
        for (int ct = 0; ct < 2; ++ct) {
          bf16x8 wvf = wql[((16 + 2 * h + ct) * 4 + kk) * 64 + lane];
          #pragma unroll
          for (int rt = 0; rt < 4; ++rt)
            vN[ct][rt] = __builtin_amdgcn_mfma_f32_16x16x32_bf16(a[rt], wvf, vN[ct][rt], 0, 0, 0);
        }
      }
      bar_lds();   // all Xb reads done; buf free for Ob

      float vb0 = v_bias[h * 32 + l15], vb1 = v_bias[h * 32 + 16 + l15];
      #pragma unroll
      for (int ks = 0; ks < 2; ++ks)
        #pragma unroll
        for (int ct = 0; ct < 2; ++ct) {
          float vb = ct ? vb1 : vb0;
          bv[ks][ct] = pack4(
              cvt_pk_bf16(vN[ct][2 * ks][0] + vb, vN[ct][2 * ks][1] + vb),
              cvt_pk_bf16(vN[ct][2 * ks][2] + vb, vN[ct][2 * ks][3] + vb),
              cvt_pk_bf16(vN[ct][2 * ks + 1][0] + vb, vN[ct][2 * ks + 1][1] + vb),
              cvt_pk_bf16(vN[ct][2 * ks + 1][2] + vb, vN[ct][2 * ks + 1][3] + vb));
        }
    }

    // ---- per q-rowtile: S^T -> softmax (max-subtracted) -> PV -> Ob
    {
      #pragma unroll
      for (int r = 0; r < 4; ++r) {
        f32x4 st[4];
        #pragma unroll
        for (int c = 0; c < 4; ++c)
          st[c] = __builtin_amdgcn_mfma_f32_16x16x32_bf16(
              bk[c], aq[r], rp[(h * 16 + r * 4 + c) * 64 + lane], 0, 0, 0);

        float mx = st[0][0];
        #pragma unroll
        for (int c = 0; c < 4; ++c)
          #pragma unroll
          for (int j = 0; j < 4; ++j) mx = fmaxf(mx, st[c][j]);
        mx = fmaxf(mx, __shfl_xor(mx, 16));
        mx = fmaxf(mx, __shfl_xor(mx, 32));

        float e[4][4];
        float sum = 0.f;
        #pragma unroll
        for (int c = 0; c < 4; ++c)
          #pragma unroll
          for (int j = 0; j < 4; ++j) { e[c][j] = __expf(st[c][j] - mx); sum += e[c][j]; }
        sum += __shfl_xor(sum, 16); sum += __shfl_xor(sum, 32);
        float rs = __fdividef(1.0f, sum);

        bf16x8 ap0 = pack4(cvt_pk_bf16(e[0][0], e[0][1]), cvt_pk_bf16(e[0][2], e[0][3]),
                           cvt_pk_bf16(e[1][0], e[1][1]), cvt_pk_bf16(e[1][2], e[1][3]));
        bf16x8 ap1 = pack4(cvt_pk_bf16(e[2][0], e[2][1]), cvt_pk_bf16(e[2][2], e[2][3]),
                           cvt_pk_bf16(e[3][0], e[3][1]), cvt_pk_bf16(e[3][2], e[3][3]));

        f32x4 o0 = __builtin_amdgcn_mfma_f32_16x16x32_bf16(bv[0][0], ap0, fzero, 0, 0, 0);
        o0 = __builtin_amdgcn_mfma_f32_16x16x32_bf16(bv[1][0], ap1, o0, 0, 0, 0);
        f32x4 o1 = __builtin_amdgcn_mfma_f32_16x16x32_bf16(bv[0][1], ap0, fzero, 0, 0, 0);
        o1 = __builtin_amdgcn_mfma_f32_16x16x32_bf16(bv[1][1], ap1, o1, 0, 0, 0);

        int n = r * 16 + l15;
        uint4 wv4 = { cvt_pk_bf16(o0[0] * rs, o0[1] * rs), cvt_pk_bf16(o0[2] * rs, o0[3] * rs),
                      cvt_pk_bf16(o1[0] * rs, o1[1] * rs), cvt_pk_bf16(o1[2] * rs, o1[3] * rs) };
        *(uint4*)(buf + ((n * 256 + h * 64 + 16 * l4) ^ ((n & 7) << 4))) = wv4;
      }
    }
    bar_lds();   // Ob ready

    // ---- Phase 5: out = Ob @ proj_w^T + proj_b; wave h -> rows [16h, 16h+16)
    {
      const int n = h * 16 + l15;
      f32x4 po[8];
      #pragma unroll
      for (int c2 = 0; c2 < 8; ++c2) po[c2] = fzero;
      #pragma unroll
      for (int kk = 0; kk < 4; ++kk) {
        bf16x8 ob = *(const bf16x8*)(buf + ((n * 256 + kk * 64 + 16 * l4) ^ swl));
        #pragma unroll
        for (int c2 = 0; c2 < 8; ++c2) {
          bf16x8 wf = wpl[(c2 * 4 + kk) * 64 + lane];
          po[c2] = __builtin_amdgcn_mfma_f32_16x16x32_bf16(wf, ob, po[c2], 0, 0, 0);
        }
      }

      // issue next window's x loads HERE: after the last weight load of this
      // iteration (in-order vmcnt => only the 8 NT stores are younger), so
      // they stay in flight through the epilogue + loop-back into next stage.
      __builtin_amdgcn_sched_barrier(0);
      if (w + 1 < nw) {
        const float4* xp = (const float4*)(x + base + 8192);
        #pragma unroll
        for (int i = 0; i < 8; ++i) pf[i] = xp[i * 256 + tid];
      }

      float* op = out + base + (long)n * 128;
      #pragma unroll
      for (int c2 = 0; c2 < 8; ++c2) {
        float4 pb = *(const float4*)&proj_b[c2 * 16 + l4 * 4];
        f32x4 v = { po[c2][0] + pb.x, po[c2][1] + pb.y,
                    po[c2][2] + pb.z, po[c2][3] + pb.w };
        // non-temporal: out is never re-read; keep x resident in L3
        __builtin_nontemporal_store(v, (f32x4*)&op[c2 * 16 + l4 * 4]);
      }
    }
  }
}

extern "C" void kernel_launch(void* const* d_in, const int* in_sizes, int n_in,
                              void* d_out, int out_size, void* d_ws, size_t ws_size,
                              hipStream_t stream) {
  (void)n_in; (void)out_size; (void)ws_size;
  const float* x           = (const float*)d_in[0];
  const float* W_qkv       = (const float*)d_in[1];
  const float* q_bias      = (const float*)d_in[2];
  const float* v_bias      = (const float*)d_in[3];
  const float* logit_scale = (const float*)d_in[4];
  const float* cpb_w1      = (const float*)d_in[5];
  const float* cpb_b1      = (const float*)d_in[6];
  const float* cpb_w2      = (const float*)d_in[7];
  const float* proj_w      = (const float*)d_in[8];
  const float* proj_b      = (const float*)d_in[9];
  const float* rel_table   = (const float*)d_in[10];
  const int*   rel_index   = (const int*)d_in[11];

  // ws: rpbf f32[16384] @0 (64KB) | wq bf16x8[6144] @64KB (96KB)
  //     | wp bf16x8[2048] @160KB (32KB)
  float*  rpbf = (float*)d_ws;
  bf16x8* wq   = (bf16x8*)((char*)d_ws + 65536);
  bf16x8* wp   = (bf16x8*)((char*)d_ws + 65536 + 98304);

  int nwin = in_sizes[0] / 8192;   // 8192 windows of 64x128
  int nblk = (nwin + WPB - 1) / WPB;

  prep<<<33, 256, 0, stream>>>(W_qkv, proj_w, cpb_w1, cpb_b1, cpb_w2,
                               rel_table, rel_index, wq, wp, rpbf);
  win_attn<<<nblk, 256, 0, stream>>>(x, q_bias, v_bias, logit_scale, proj_b,
                                     rpbf, wq, wp, (float*)d_out, nwin);
}

// Round 4
// 221.136 us; speedup vs baseline: 3.5322x; 3.5322x over previous
//
#include <hip/hip_runtime.h>

typedef short bf16x8 __attribute__((ext_vector_type(8)));
typedef float f32x4 __attribute__((ext_vector_type(4)));

__device__ __forceinline__ unsigned cvt_pk_bf16(float lo, float hi) {
  unsigned r;
  asm("v_cvt_pk_bf16_f32 %0, %1, %2" : "=v"(r) : "v"(lo), "v"(hi));
  return r;
}

__device__ __forceinline__ bf16x8 pack4(unsigned a, unsigned b, unsigned c, unsigned d) {
  union { unsigned u[4]; bf16x8 v; } t;
  t.u[0] = a; t.u[1] = b; t.u[2] = c; t.u[3] = d;
  return t.v;
}

__device__ __forceinline__ unsigned short f2bf(float f) {
  unsigned u = __float_as_uint(f);
  unsigned r = (u + 0x7fffu + ((u >> 16) & 1u)) >> 16;
  return (unsigned short)r;
}

// ---------------------------------------------------------------------------
// Prep kernel:
//  blocks 0..31 : W_qkv (6144 frags, contiguous k) and proj_w (2048 frags,
//                 PERMUTED k to match the in-register Ob channel order:
//                 k-slot kk*32+8*g+j  ->  orig channel kk*32+(j>>2)*16+4*g+(j&3))
//  block 32     : CPB MLP -> rpb packed as MFMA C-fragments for swapped S^T
// ---------------------------------------------------------------------------
__global__ __launch_bounds__(256) void prep(
    const float* __restrict__ W_qkv, const float* __restrict__ proj_w,
    const float* __restrict__ cpb_w1, const float* __restrict__ cpb_b1,
    const float* __restrict__ cpb_w2, const float* __restrict__ rel_table,
    const int* __restrict__ rel_index,
    bf16x8* __restrict__ wq, bf16x8* __restrict__ wp, float* __restrict__ rpbf)
{
  const int b = blockIdx.x, t = threadIdx.x;
  if (b < 32) {
    int g = b * 256 + t;               // [0, 8192)
    if (g < 6144) {
      int c = g >> 8, kk = (g >> 6) & 3, l = g & 63;
      const float* s = W_qkv + (c * 16 + (l & 15)) * 128 + kk * 32 + (l >> 4) * 8;
      bf16x8 v;
      #pragma unroll
      for (int j = 0; j < 8; ++j) v[j] = (short)f2bf(s[j]);
      wq[g] = v;
    } else {
      int gl = g - 6144;
      int c = gl >> 8, kk = (gl >> 6) & 3, l = gl & 63;
      const float* row = proj_w + (c * 16 + (l & 15)) * 128;
      bf16x8 v;
      #pragma unroll
      for (int j = 0; j < 8; ++j)
        v[j] = (short)f2bf(row[kk * 32 + (j >> 2) * 16 + (l >> 4) * 4 + (j & 3)]);
      wp[gl] = v;
    }
  } else {
    __shared__ float bt[900];
    if (t < 225) {
      float t0 = rel_table[t * 2], t1 = rel_table[t * 2 + 1];
      float a0 = 0.f, a1 = 0.f, a2 = 0.f, a3 = 0.f;
      for (int j = 0; j < 512; ++j) {
        float hm = fmaxf(t0 * cpb_w1[j * 2] + t1 * cpb_w1[j * 2 + 1] + cpb_b1[j], 0.f);
        a0 += hm * cpb_w2[j];
        a1 += hm * cpb_w2[512 + j];
        a2 += hm * cpb_w2[1024 + j];
        a3 += hm * cpb_w2[1536 + j];
      }
      bt[t * 4 + 0] = a0; bt[t * 4 + 1] = a1;
      bt[t * 4 + 2] = a2; bt[t * 4 + 3] = a3;
    }
    __syncthreads();
    for (int i = t; i < 16384; i += 256) {
      int hrc = i >> 8, lane = (i >> 2) & 63, j = i & 3;
      int hh = hrc >> 4, r = (hrc >> 2) & 3, c = hrc & 3;
      int n = r * 16 + (lane & 15);
      int m = c * 16 + ((lane >> 4) << 2) + j;
      float v = bt[rel_index[n * 64 + m] * 4 + hh];
      rpbf[i] = 16.0f * __fdividef(1.0f, 1.0f + __expf(-v));
    }
  }
}

// ---------------------------------------------------------------------------
// Fused window attention, register-resident, pressure-split edition.
// ROUND 4: exact round-0 body (the only verified-good configuration:
// 212us, 84 VGPR, no spills) + ONE delta: non-temporal out-stores.
// Rationale: out writes 256MB/launch through L3 while x (exactly 256MB) is
// ~half L3-served (FETCH 132MB). NT stores stop out from evicting x.
// The rounds-1..3 multi-window pipeline (WPB loop + LICM pin asm +
// sched_barrier prefetch) is abandoned: it failed deterministically under
// the spill-free (256,3) allocation even with full __syncthreads, i.e. the
// failure is in that body's codegen interaction, not in barrier choice.
// 256 threads = 4 waves, wave h owns head h end-to-end.
// Softmax is max-subtracted (exp args <= 0: overflow impossible).
// LDS = 16 KB: Xb bf16[64][128] (phases 0-1) overlaid by Ob (phases 4-5),
// XOR-swizzled (addr ^ ((row&7)<<4)). 3 barriers total.
// ---------------------------------------------------------------------------
__global__ __launch_bounds__(256, 3) void win_attn(
    const float* __restrict__ x,
    const float* __restrict__ q_bias,
    const float* __restrict__ v_bias,
    const float* __restrict__ logit_scale,
    const float* __restrict__ proj_b,
    const float* __restrict__ rpbf,
    const bf16x8* __restrict__ wq,
    const bf16x8* __restrict__ wp,
    float* __restrict__ out)
{
  __shared__ __align__(128) char lds[16384];
  const int tid  = threadIdx.x;
  const int lane = tid & 63;
  const int h    = tid >> 6;     // wave = head
  const int l15  = lane & 15;
  const int l4   = lane >> 4;
  const int swl  = (l15 & 7) << 4;
  const long base = (long)blockIdx.x * 8192;
  const f32x4 fzero = {0.f, 0.f, 0.f, 0.f};

  // ---- Phase 0: stage x window -> swizzled bf16 Xb[64][128]
  {
    const float4* xp = (const float4*)(x + base);
    #pragma unroll
    for (int i = 0; i < 8; ++i) {
      float4 v = xp[i * 256 + tid];
      int e   = (i * 256 + tid) * 4;
      int row = e >> 7;
      int cb  = (e & 127) * 2;
      uint2 pk = { cvt_pk_bf16(v.x, v.y), cvt_pk_bf16(v.z, v.w) };
      *(uint2*)(lds + ((row * 256 + cb) ^ ((row & 7) << 4))) = pk;
    }
  }
  __syncthreads();

  bf16x8 aq[4], bk[4], bv[2][2];

  // ---- Phase 1a: q,k GEMM (swapped: lane d = ct*16+4*l4+reg, n = rt*16+l15)
  {
    f32x4 qT[2][4], kT[2][4];
    #pragma unroll
    for (int ct = 0; ct < 2; ++ct)
      #pragma unroll
      for (int rt = 0; rt < 4; ++rt) { qT[ct][rt] = fzero; kT[ct][rt] = fzero; }

    #pragma unroll
    for (int kk = 0; kk < 4; ++kk) {
      bf16x8 a[4];
      #pragma unroll
      for (int rt = 0; rt < 4; ++rt) {
        int row = rt * 16 + l15;
        a[rt] = *(const bf16x8*)(lds + ((row * 256 + kk * 64 + l4 * 16) ^ swl));
      }
      #pragma unroll
      for (int ct = 0; ct < 2; ++ct) {
        bf16x8 wqf = wq[((2 * h + ct) * 4 + kk) * 64 + lane];
        bf16x8 wkf = wq[((8 + 2 * h + ct) * 4 + kk) * 64 + lane];
        #pragma unroll
        for (int rt = 0; rt < 4; ++rt) {
          qT[ct][rt] = __builtin_amdgcn_mfma_f32_16x16x32_bf16(wqf, a[rt], qT[ct][rt], 0, 0, 0);
          kT[ct][rt] = __builtin_amdgcn_mfma_f32_16x16x32_bf16(wkf, a[rt], kT[ct][rt], 0, 0, 0);
        }
      }
    }

    // ---- normalize q,k; pack S-fragments, lane-local (d-permuted)
    float scale = __expf(fminf(logit_scale[h], 4.6051701859880914f)); // log(100)
    float4 qb0 = *(const float4*)&q_bias[h * 32 + l4 * 4];
    float4 qb1 = *(const float4*)&q_bias[h * 32 + 16 + l4 * 4];
    #pragma unroll
    for (int rt = 0; rt < 4; ++rt) {
      float tq0 = qT[0][rt][0] + qb0.x, tq1 = qT[0][rt][1] + qb0.y;
      float tq2 = qT[0][rt][2] + qb0.z, tq3 = qT[0][rt][3] + qb0.w;
      float tq4 = qT[1][rt][0] + qb1.x, tq5 = qT[1][rt][1] + qb1.y;
      float tq6 = qT[1][rt][2] + qb1.z, tq7 = qT[1][rt][3] + qb1.w;
      float sq = tq0*tq0 + tq1*tq1 + tq2*tq2 + tq3*tq3
               + tq4*tq4 + tq5*tq5 + tq6*tq6 + tq7*tq7;
      float sk = kT[0][rt][0]*kT[0][rt][0] + kT[0][rt][1]*kT[0][rt][1]
               + kT[0][rt][2]*kT[0][rt][2] + kT[0][rt][3]*kT[0][rt][3]
               + kT[1][rt][0]*kT[1][rt][0] + kT[1][rt][1]*kT[1][rt][1]
               + kT[1][rt][2]*kT[1][rt][2] + kT[1][rt][3]*kT[1][rt][3];
      sq += __shfl_xor(sq, 16); sq += __shfl_xor(sq, 32);
      sk += __shfl_xor(sk, 16); sk += __shfl_xor(sk, 32);
      float iq = __fdividef(scale, fmaxf(sqrtf(sq), 1e-12f));
      float ik = __fdividef(1.0f,  fmaxf(sqrtf(sk), 1e-12f));
      aq[rt] = pack4(cvt_pk_bf16(tq0 * iq, tq1 * iq), cvt_pk_bf16(tq2 * iq, tq3 * iq),
                     cvt_pk_bf16(tq4 * iq, tq5 * iq), cvt_pk_bf16(tq6 * iq, tq7 * iq));
      bk[rt] = pack4(cvt_pk_bf16(kT[0][rt][0] * ik, kT[0][rt][1] * ik),
                     cvt_pk_bf16(kT[0][rt][2] * ik, kT[0][rt][3] * ik),
                     cvt_pk_bf16(kT[1][rt][0] * ik, kT[1][rt][1] * ik),
                     cvt_pk_bf16(kT[1][rt][2] * ik, kT[1][rt][3] * ik));
    }
  }

  // ---- Phase 1b: v GEMM (normal: lane m = rt*16+4*l4+reg, d = ct*16+l15)
  {
    f32x4 vN[2][4];
    #pragma unroll
    for (int ct = 0; ct < 2; ++ct)
      #pragma unroll
      for (int rt = 0; rt < 4; ++rt) vN[ct][rt] = fzero;

    #pragma unroll
    for (int kk = 0; kk < 4; ++kk) {
      bf16x8 a[4];
      #pragma unroll
      for (int rt = 0; rt < 4; ++rt) {
        int row = rt * 16 + l15;
        a[rt] = *(const bf16x8*)(lds + ((row * 256 + kk * 64 + l4 * 16) ^ swl));
      }
      #pragma unroll
      for (int ct = 0; ct < 2; ++ct) {
        bf16x8 wvf = wq[((16 + 2 * h + ct) * 4 + kk) * 64 + lane];
        #pragma unroll
        for (int rt = 0; rt < 4; ++rt)
          vN[ct][rt] = __builtin_amdgcn_mfma_f32_16x16x32_bf16(a[rt], wvf, vN[ct][rt], 0, 0, 0);
      }
    }
    __syncthreads();   // all Xb reads done; [0,16K) free for Ob

    float vb0 = v_bias[h * 32 + l15], vb1 = v_bias[h * 32 + 16 + l15];
    #pragma unroll
    for (int ks = 0; ks < 2; ++ks)
      #pragma unroll
      for (int ct = 0; ct < 2; ++ct) {
        float vb = ct ? vb1 : vb0;
        bv[ks][ct] = pack4(
            cvt_pk_bf16(vN[ct][2 * ks][0] + vb, vN[ct][2 * ks][1] + vb),
            cvt_pk_bf16(vN[ct][2 * ks][2] + vb, vN[ct][2 * ks][3] + vb),
            cvt_pk_bf16(vN[ct][2 * ks + 1][0] + vb, vN[ct][2 * ks + 1][1] + vb),
            cvt_pk_bf16(vN[ct][2 * ks + 1][2] + vb, vN[ct][2 * ks + 1][3] + vb));
      }
  }

  // ---- per q-rowtile: S^T -> softmax (max-subtracted) -> PV -> Ob
  {
    const f32x4* rp = (const f32x4*)rpbf;
    #pragma unroll
    for (int r = 0; r < 4; ++r) {
      f32x4 st[4];
      #pragma unroll
      for (int c = 0; c < 4; ++c)
        st[c] = __builtin_amdgcn_mfma_f32_16x16x32_bf16(
            bk[c], aq[r], rp[(h * 16 + r * 4 + c) * 64 + lane], 0, 0, 0);

      float mx = st[0][0];
      #pragma unroll
      for (int c = 0; c < 4; ++c)
        #pragma unroll
        for (int j = 0; j < 4; ++j) mx = fmaxf(mx, st[c][j]);
      mx = fmaxf(mx, __shfl_xor(mx, 16));
      mx = fmaxf(mx, __shfl_xor(mx, 32));

      float e[4][4];
      float sum = 0.f;
      #pragma unroll
      for (int c = 0; c < 4; ++c)
        #pragma unroll
        for (int j = 0; j < 4; ++j) { e[c][j] = __expf(st[c][j] - mx); sum += e[c][j]; }
      sum += __shfl_xor(sum, 16); sum += __shfl_xor(sum, 32);
      float rs = __fdividef(1.0f, sum);

      bf16x8 ap0 = pack4(cvt_pk_bf16(e[0][0], e[0][1]), cvt_pk_bf16(e[0][2], e[0][3]),
                         cvt_pk_bf16(e[1][0], e[1][1]), cvt_pk_bf16(e[1][2], e[1][3]));
      bf16x8 ap1 = pack4(cvt_pk_bf16(e[2][0], e[2][1]), cvt_pk_bf16(e[2][2], e[2][3]),
                         cvt_pk_bf16(e[3][0], e[3][1]), cvt_pk_bf16(e[3][2], e[3][3]));

      f32x4 o0 = __builtin_amdgcn_mfma_f32_16x16x32_bf16(bv[0][0], ap0, fzero, 0, 0, 0);
      o0 = __builtin_amdgcn_mfma_f32_16x16x32_bf16(bv[1][0], ap1, o0, 0, 0, 0);
      f32x4 o1 = __builtin_amdgcn_mfma_f32_16x16x32_bf16(bv[0][1], ap0, fzero, 0, 0, 0);
      o1 = __builtin_amdgcn_mfma_f32_16x16x32_bf16(bv[1][1], ap1, o1, 0, 0, 0);

      int n = r * 16 + l15;
      uint4 w = { cvt_pk_bf16(o0[0] * rs, o0[1] * rs), cvt_pk_bf16(o0[2] * rs, o0[3] * rs),
                  cvt_pk_bf16(o1[0] * rs, o1[1] * rs), cvt_pk_bf16(o1[2] * rs, o1[3] * rs) };
      *(uint4*)(lds + ((n * 256 + h * 64 + 16 * l4) ^ ((n & 7) << 4))) = w;
    }
  }
  __syncthreads();   // Ob ready

  // ---- Phase 5: out = Ob @ proj_w^T + proj_b; wave h -> rows [16h, 16h+16)
  //      (whole rows per wave -> full-line fp32 stores; wp pre-permuted)
  {
    const int n = h * 16 + l15;
    f32x4 po[8];
    #pragma unroll
    for (int c2 = 0; c2 < 8; ++c2) po[c2] = fzero;
    #pragma unroll
    for (int kk = 0; kk < 4; ++kk) {
      bf16x8 ob = *(const bf16x8*)(lds + ((n * 256 + kk * 64 + 16 * l4) ^ swl));
      #pragma unroll
      for (int c2 = 0; c2 < 8; ++c2) {
        bf16x8 wf = wp[(c2 * 4 + kk) * 64 + lane];
        po[c2] = __builtin_amdgcn_mfma_f32_16x16x32_bf16(wf, ob, po[c2], 0, 0, 0);
      }
    }
    float* op = out + base + (long)n * 128;
    #pragma unroll
    for (int c2 = 0; c2 < 8; ++c2) {
      float4 pb = *(const float4*)&proj_b[c2 * 16 + l4 * 4];
      f32x4 v = { po[c2][0] + pb.x, po[c2][1] + pb.y,
                  po[c2][2] + pb.z, po[c2][3] + pb.w };
      // ROUND-4 DELTA: non-temporal store — out is never re-read; stop it
      // from evicting x (exactly 256MB) from the 256MB L3.
      __builtin_nontemporal_store(v, (f32x4*)&op[c2 * 16 + l4 * 4]);
    }
  }
}

extern "C" void kernel_launch(void* const* d_in, const int* in_sizes, int n_in,
                              void* d_out, int out_size, void* d_ws, size_t ws_size,
                              hipStream_t stream) {
  (void)n_in; (void)out_size; (void)ws_size;
  const float* x           = (const float*)d_in[0];
  const float* W_qkv       = (const float*)d_in[1];
  const float* q_bias      = (const float*)d_in[2];
  const float* v_bias      = (const float*)d_in[3];
  const float* logit_scale = (const float*)d_in[4];
  const float* cpb_w1      = (const float*)d_in[5];
  const float* cpb_b1      = (const float*)d_in[6];
  const float* cpb_w2      = (const float*)d_in[7];
  const float* proj_w      = (const float*)d_in[8];
  const float* proj_b      = (const float*)d_in[9];
  const float* rel_table   = (const float*)d_in[10];
  const int*   rel_index   = (const int*)d_in[11];

  // ws: rpbf f32[16384] @0 (64KB) | wq bf16x8[6144] @64KB (96KB)
  //     | wp bf16x8[2048] @160KB (32KB)
  float*  rpbf = (float*)d_ws;
  bf16x8* wq   = (bf16x8*)((char*)d_ws + 65536);
  bf16x8* wp   = (bf16x8*)((char*)d_ws + 65536 + 98304);

  int nwin = in_sizes[0] / 8192;   // 8192 windows of 64x128

  prep<<<33, 256, 0, stream>>>(W_qkv, proj_w, cpb_w1, cpb_b1, cpb_w2,
                               rel_table, rel_index, wq, wp, rpbf);
  win_attn<<<nwin, 256, 0, stream>>>(x, q_bias, v_bias, logit_scale, proj_b,
                                     rpbf, wq, wp, (float*)d_out);
}